// Round 3
// baseline (2976.061 us; speedup 1.0000x reference)
//
#include <hip/hip_runtime.h>

// Problem constants (SpatialEncoding_46943992545790)
#define T_STEPS 4
#define NN 50000
#define EE 800000
#define DD 256
#define VOCAB 64000
#define NB ((NN + 255) / 256)   // 196 scan blocks
#define SLICES 8                // feature slices: 32 bf16 = 64 B each; 3.2 MB/slice table
#define NBLK_C ((NN + 3) / 4)   // c-blocks per slice (4 waves/block, 1 c/wave)

typedef __attribute__((ext_vector_type(8))) short short8;
typedef __attribute__((ext_vector_type(4))) float floatx4;

// ---------------------------------------------------------------- bf16 helpers
__device__ __forceinline__ unsigned short f2bf(float f) {
    unsigned u = __float_as_uint(f);
    return (unsigned short)((u + 0x7FFFu + ((u >> 16) & 1u)) >> 16);  // RNE
}
__device__ __forceinline__ float bf2f(unsigned short s) {
    return __uint_as_float(((unsigned)s) << 16);
}

__device__ __forceinline__ void async16(const unsigned short* g, unsigned short* l) {
    __builtin_amdgcn_global_load_lds(
        (const __attribute__((address_space(1))) void*)g,
        (__attribute__((address_space(3))) void*)l, 16, 0, 0);
}

// ---------------------------------------------------------------- init
__global__ __launch_bounds__(256) void init_deg_cnt(float* __restrict__ deg,
                                                    int* __restrict__ cnt, int n) {
    int i = blockIdx.x * 256 + threadIdx.x;
    if (i < n) { deg[i] = 1.0f; cnt[i] = 0; }   // self-loop weight 1
}

// ------------------------------------------------- edge pass: deg + counts
__global__ __launch_bounds__(256) void edge_deg_cnt(const int* __restrict__ col,
                                                    const float* __restrict__ w,
                                                    float* __restrict__ deg,
                                                    int* __restrict__ cnt, int e) {
    int i = blockIdx.x * 256 + threadIdx.x;
    if (i < e) {
        int c = col[i];
        atomicAdd(&deg[c], w[i]);
        atomicAdd(&cnt[c], 1);
    }
}

// ------------------------------- fused: dinv + s1 self-seed + scan pass 1
__global__ __launch_bounds__(256) void dinv_bsums(const float* __restrict__ deg,
                                                  float* __restrict__ dinv,
                                                  float* __restrict__ s1,
                                                  const int* __restrict__ cnt,
                                                  int* __restrict__ bsum, int n) {
    int i = blockIdx.x * 256 + threadIdx.x;
    if (i < n) {
        float d = deg[i];
        float r = d > 0.0f ? rsqrtf(d) : 0.0f;
        dinv[i] = r;
        s1[i] = r * r;            // self-loop contribution to s1 = A·1
    }
    __shared__ int sm[256];
    sm[threadIdx.x] = (i < n) ? cnt[i] : 0;
    __syncthreads();
    for (int s = 128; s > 0; s >>= 1) {
        if ((int)threadIdx.x < s) sm[threadIdx.x] += sm[threadIdx.x + s];
        __syncthreads();
    }
    if (threadIdx.x == 0) bsum[blockIdx.x] = sm[0];
}

// --------------------------------------------------- parallel scan, pass 2
__global__ __launch_bounds__(256) void scan_bsum(const int* __restrict__ bsum,
                                                 int* __restrict__ boff, int nb) {
    __shared__ int sm[256];
    int v = ((int)threadIdx.x < nb) ? bsum[threadIdx.x] : 0;
    sm[threadIdx.x] = v;
    __syncthreads();
    for (int o = 1; o < 256; o <<= 1) {
        int t = (threadIdx.x >= (unsigned)o) ? sm[threadIdx.x - o] : 0;
        __syncthreads();
        sm[threadIdx.x] += t;
        __syncthreads();
    }
    if ((int)threadIdx.x < nb) boff[threadIdx.x] = sm[threadIdx.x] - v;
}

// --------------------------------------------------- parallel scan, pass 3
__global__ __launch_bounds__(256) void scan_final(const int* __restrict__ cnt,
                                                  const int* __restrict__ boff,
                                                  int* __restrict__ colptr,
                                                  int* __restrict__ next, int n, int e) {
    __shared__ int sm[256];
    int i = blockIdx.x * 256 + threadIdx.x;
    int v = (i < n) ? cnt[i] : 0;
    sm[threadIdx.x] = v;
    __syncthreads();
    for (int o = 1; o < 256; o <<= 1) {
        int t = (threadIdx.x >= (unsigned)o) ? sm[threadIdx.x - o] : 0;
        __syncthreads();
        sm[threadIdx.x] += t;
        __syncthreads();
    }
    int excl = sm[threadIdx.x] - v + boff[blockIdx.x];
    if (i < n) { colptr[i] = excl; next[i] = excl; }
    if (i == 0) colptr[n] = e;   // every edge's col is in [0,n)
}

// --------------------------------------- fill CSR (packed edges) + s1 atomics
__global__ __launch_bounds__(256) void fill_csr(const int* __restrict__ row,
                                                const int* __restrict__ col,
                                                const float* __restrict__ w,
                                                const float* __restrict__ dinv,
                                                int* __restrict__ next,
                                                int2* __restrict__ edges,
                                                float* __restrict__ s1, int e) {
    int i = blockIdx.x * 256 + threadIdx.x;
    if (i < e) {
        int r = row[i], c = col[i];
        float nm = dinv[r] * w[i] * dinv[c];
        int p = atomicAdd(&next[c], 1);
        edges[p] = make_int2(r, __float_as_int(nm));
        atomicAdd(&s1[c], nm);     // completes s1 = A·1 (self seeded in dinv_bsums)
    }
}

// --------------------------------- fp32 256x256 matmul: C = A @ B (once/launch)
__global__ __launch_bounds__(256) void matmul256(const float* __restrict__ A,
                                                 const float* __restrict__ B,
                                                 float* __restrict__ C) {
    __shared__ float arow[256];
    int i = blockIdx.x, j = threadIdx.x;
    arow[j] = A[i * 256 + j];
    __syncthreads();
    float acc = 0.f;
#pragma unroll 8
    for (int k = 0; k < 256; ++k) acc += arow[k] * B[k * 256 + j];
    C[i * 256 + j] = acc;
}

// --------------------------------- fp32 matvec: y = x @ W  (1 block, once/launch)
__global__ __launch_bounds__(256) void matvec256(const float* __restrict__ x,
                                                 const float* __restrict__ W,
                                                 float* __restrict__ y) {
    __shared__ float xs[256];
    int j = threadIdx.x;
    xs[j] = x[j];
    __syncthreads();
    float acc = 0.f;
#pragma unroll 8
    for (int k = 0; k < 256; ++k) acc += xs[k] * W[k * 256 + j];
    y[j] = acc;
}

// --------------------------------- Wc[k][n] fp32 -> wt[n][k] bf16 (transposed)
__global__ __launch_bounds__(256) void convert_wc(const float* __restrict__ Wc,
                                                  unsigned short* __restrict__ wt) {
    int n = blockIdx.x;          // 0..255
    int k = threadIdx.x;         // 0..255
    wt[n * 256 + k] = f2bf(Wc[k * 256 + n]);
}

// --------------------------------- emb fp32 -> bf16 (once per launch)
__global__ __launch_bounds__(256) void convert_emb(const float* __restrict__ emb,
                                                   unsigned short* __restrict__ ebf,
                                                   int total4) {
    int t = blockIdx.x * 256 + threadIdx.x;
    if (t < total4) {
        float4 v = ((const float4*)emb)[t];
        ushort4 o;
        o.x = f2bf(v.x); o.y = f2bf(v.y); o.z = f2bf(v.z); o.w = f2bf(v.w);
        ((ushort4*)ebf)[t] = o;
    }
}

// ------------------------------------------------------- bf16 MFMA GEMM + gather
// Z = ebf[ids[M],256] @ Wc, written SLICE-MAJOR: h2[slice][node][32] bf16
// (slice = col>>5) so aggregation slices are contiguous 3.2 MB L2-resident blocks.
// BM=128, BN=256, BK=32, 4 waves; wave = 64x128 via 4x8 grid of 16x16x32 MFMA.
__global__ __launch_bounds__(256) void mfma_gemm(const int* __restrict__ ids,
                                                 const unsigned short* __restrict__ ebf,
                                                 const unsigned short* __restrict__ wt,
                                                 unsigned short* __restrict__ h2,
                                                 int M) {
    __shared__ __align__(16) unsigned short As[128 * 32];   // 8 KB
    __shared__ __align__(16) unsigned short Bs[256 * 32];   // 16 KB

    int tid = threadIdx.x;
    int lane = tid & 63;
    int wave = tid >> 6;
    int row0 = blockIdx.x * 128;
    int wm = (wave & 1) * 64;
    int wn = (wave >> 1) * 128;
    int quad = lane >> 4;
    int cl = lane & 15;

    // A staging: 2 units/thread, u = s*256+tid; c = u>>7 (k-chunk), m = u&127
    int uA0 = tid, uA1 = 256 + tid;
    int cA0 = uA0 >> 7, mA0 = uA0 & 127;
    int cA1 = uA1 >> 7;                       // same row (uA1&127 == mA0)
    int gr = row0 + mA0; if (gr >= M) gr = M - 1;
    int id0 = ids[gr];                        // embedding gather index
    const unsigned short* srcA0 = ebf + (size_t)id0 * 256 + cA0 * 8;
    const unsigned short* srcA1 = ebf + (size_t)id0 * 256 + cA1 * 8;
    unsigned short* dstA0 = As + uA0 * 8;
    unsigned short* dstA1 = As + uA1 * 8;

    // B staging: 4 units/thread, unit s: chunk=s, n=tid
    const unsigned short* srcB = wt + (size_t)tid * 256;
    unsigned short* dstBbase = Bs + tid * 8;

    floatx4 acc[4][8] = {};

    for (int k0 = 0; k0 < 256; k0 += 32) {
        if (k0) __syncthreads();          // protect LDS from prior reads
        async16(srcA0 + k0, dstA0);
        async16(srcA1 + k0, dstA1);
#pragma unroll
        for (int s5 = 0; s5 < 4; ++s5)
            async16(srcB + s5 * 8 + k0, dstBbase + s5 * 2048);
        __syncthreads();                  // drains vmcnt before barrier

        short8 af[4], bfr[8];
#pragma unroll
        for (int i = 0; i < 4; ++i)
            af[i] = *(const short8*)&As[(quad * 128 + wm + i * 16 + cl) * 8];
#pragma unroll
        for (int j = 0; j < 8; ++j)
            bfr[j] = *(const short8*)&Bs[(quad * 256 + wn + j * 16 + cl) * 8];
#pragma unroll
        for (int i = 0; i < 4; ++i)
#pragma unroll
            for (int j = 0; j < 8; ++j)
                acc[i][j] = __builtin_amdgcn_mfma_f32_16x16x32_bf16(
                    af[i], bfr[j], acc[i][j], 0, 0, 0);
    }

    // epilogue -> slice-major: D[row=quad*4+reg][col=lane&15] per 16x16 tile
#pragma unroll
    for (int i = 0; i < 4; ++i) {
#pragma unroll
        for (int r = 0; r < 4; ++r) {
            int gr2 = row0 + wm + i * 16 + quad * 4 + r;
            if (gr2 < M) {
#pragma unroll
                for (int j = 0; j < 8; ++j) {
                    int colf = wn + j * 16 + cl;            // 0..255
                    int slice = colf >> 5, off = colf & 31;
                    h2[((size_t)slice * M + gr2) * 32 + off] = f2bf(acc[i][j][r]);
                }
            }
        }
    }
}

// ------------------------------------------- sliced CSR aggregate (bf16 gather)
// Grid = SLICES * NBLK_C blocks; slice = blockIdx.x / NBLK_C, so (by dispatch
// order) one 3.2 MB slice is hot in each XCD's L2 at a time -> gathers hit L2.
// Wave handles one dest c: 16 edge-groups x 4 lanes x 16 B cover 16 edges/iter.
// Reduce over edge-groups via shfl_xor {4,8,16,32}; e==0 group writes 64 B.
// agg1 (slice 0 only): s2[c] = self*s1[c] + sum(norm * s1[src]).
// final: adds s2[c]*v1 + s1[c]*v2 + b3, writes fp32 row-major out.
__global__ __launch_bounds__(256) void agg_sliced(const unsigned short* __restrict__ tbl,
                                                  const int* __restrict__ colptr,
                                                  const int2* __restrict__ edges,
                                                  const float* __restrict__ dinv,
                                                  const float* __restrict__ s1,
                                                  float* __restrict__ s2_out,
                                                  const float* __restrict__ s2,
                                                  const float* __restrict__ v1,
                                                  const float* __restrict__ v2,
                                                  const float* __restrict__ b3,
                                                  float* __restrict__ dstf,
                                                  unsigned short* __restrict__ dstb,
                                                  int n) {
    int slice = blockIdx.x / NBLK_C;
    int cblk  = blockIdx.x % NBLK_C;
    int wave = threadIdx.x >> 6;
    int lane = threadIdx.x & 63;
    int e  = lane >> 2;          // edge group 0..15
    int f4 = lane & 3;           // 16 B chunk of the 64 B slice row
    int c = cblk * 4 + wave;
    if (c >= n) return;
    int p0 = colptr[c];
    int p1 = colptr[c + 1];
    float di = dinv[c];
    float self = di * di;
    bool do_s2 = (s2_out != nullptr) && (slice == 0);

    const unsigned short* tb = tbl + (size_t)slice * n * 32;
    float acc[8] = {};
    float ss = 0.f;

    if (e == 0) {                // self-loop term, e==0 group only
        short8 v = *(const short8*)(tb + (size_t)c * 32 + f4 * 8);
#pragma unroll
        for (int k = 0; k < 8; ++k) acc[k] += self * bf2f((unsigned short)v[k]);
    }

    for (int j0 = p0; j0 < p1; j0 += 16) {
        int jj = j0 + e;
        if (jj < p1) {
            int2 ed = edges[jj];                 // 4 lanes same addr (L1 broadcast)
            float w = __int_as_float(ed.y);
            short8 v = *(const short8*)(tb + (size_t)ed.x * 32 + f4 * 8);
            if (do_s2 && f4 == 0) ss += w * s1[ed.x];
#pragma unroll
            for (int k = 0; k < 8; ++k) acc[k] += w * bf2f((unsigned short)v[k]);
        }
    }

    // reduce over the 16 edge groups (xor masks preserve f4 class)
#pragma unroll
    for (int m = 4; m <= 32; m <<= 1) {
#pragma unroll
        for (int k = 0; k < 8; ++k) acc[k] += __shfl_xor(acc[k], m, 64);
        if (do_s2) ss += __shfl_xor(ss, m, 64);
    }
    if (do_s2 && lane == 0) s2_out[c] = self * s1[c] + ss;

    if (e == 0) {
        if (dstb) {
            short8 o;
#pragma unroll
            for (int k = 0; k < 8; ++k) o[k] = (short)f2bf(acc[k]);
            *(short8*)(dstb + ((size_t)slice * n + c) * 32 + f4 * 8) = o;
        } else {
            int f0 = slice * 32 + f4 * 8;
            float s1c = s1[c], s2c = s2[c];
            float ob[8];
#pragma unroll
            for (int k = 0; k < 8; ++k)
                ob[k] = acc[k] + s2c * v1[f0 + k] + s1c * v2[f0 + k] + b3[f0 + k];
            float* o = dstf + (size_t)c * 256 + f0;
            ((float4*)o)[0] = make_float4(ob[0], ob[1], ob[2], ob[3]);
            ((float4*)o)[1] = make_float4(ob[4], ob[5], ob[6], ob[7]);
        }
    }
}

// ----------------------------------------------------------------------
// Linearity collapse: no nonlinearity between GCN layers, so
//   out_t = A^3 · emb[ids] · (W1 W2 W3) + (A^2 1)⊗(b1 W2 W3) + (A 1)⊗(b2 W3) + 1⊗b3
// One GEMM (embedding gather fused into A-staging) + 3 sliced sparse aggs per t.
extern "C" void kernel_launch(void* const* d_in, const int* in_sizes, int n_in,
                              void* d_out, int out_size, void* d_ws, size_t ws_size,
                              hipStream_t stream) {
    const int*   node_features = (const int*)d_in[0];   // [T, N]
    const int*   edge_index    = (const int*)d_in[1];   // [T, 2, E]
    const float* edge_weight   = (const float*)d_in[2]; // [T, E]
    const float* emb           = (const float*)d_in[3]; // [VOCAB, D]
    const float* W1 = (const float*)d_in[4];
    const float* b1 = (const float*)d_in[5];
    const float* W2 = (const float*)d_in[6];
    const float* b2 = (const float*)d_in[7];
    const float* W3 = (const float*)d_in[8];
    const float* b3 = (const float*)d_in[9];
    float* out = (float*)d_out;

    // workspace layout
    char* ws = (char*)d_ws;
    size_t off = 0;
    auto alloc = [&](size_t bytes) -> void* {
        void* p = ws + off;
        off = (off + bytes + 255) & ~(size_t)255;
        return p;
    };
    unsigned short* ebf    = (unsigned short*)alloc((size_t)VOCAB * DD * 2); // bf16 emb
    unsigned short* xb     = (unsigned short*)alloc((size_t)NN * DD * 2);    // bf16 sliced
    unsigned short* h2     = (unsigned short*)alloc((size_t)NN * DD * 2);    // bf16 sliced
    unsigned short* wtc    = (unsigned short*)alloc((size_t)DD * DD * 2);    // Wc^T bf16
    float* Wtmp   = (float*)alloc((size_t)DD * DD * 4);   // W1@W2
    float* Wc32   = (float*)alloc((size_t)DD * DD * 4);   // W1@W2@W3
    float* u      = (float*)alloc((size_t)DD * 4);        // b1@W2
    float* v1     = (float*)alloc((size_t)DD * 4);        // b1@W2@W3
    float* v2     = (float*)alloc((size_t)DD * 4);        // b2@W3
    float* deg    = (float*)alloc((size_t)NN * 4);
    float* dinv   = (float*)alloc((size_t)NN * 4);
    float* s1v    = (float*)alloc((size_t)NN * 4);
    float* s2v    = (float*)alloc((size_t)NN * 4);
    int*   cnt    = (int*)alloc((size_t)NN * 4);
    int*   colptr = (int*)alloc((size_t)(NN + 1) * 4);
    int*   next   = (int*)alloc((size_t)NN * 4);
    int2*  edges  = (int2*)alloc((size_t)EE * 8);
    int*   bsum   = (int*)alloc((size_t)NB * 4);
    int*   boff   = (int*)alloc((size_t)NB * 4);
    (void)ws_size; (void)n_in; (void)in_sizes; (void)out_size;

    const int gN    = (NN + 255) / 256;   // == NB
    const int gE    = (EE + 255) / 256;
    const int gAgg  = SLICES * NBLK_C;    // sliced aggregation grid
    const int gEmb  = (VOCAB * 64 + 255) / 256;
    const int gGemm = (NN + 127) / 128;

    // ---- once per launch: collapsed weights, bias vectors, bf16 emb table
    convert_emb<<<gEmb, 256, 0, stream>>>(emb, ebf, VOCAB * 64);
    matmul256<<<256, 256, 0, stream>>>(W1, W2, Wtmp);
    matmul256<<<256, 256, 0, stream>>>(Wtmp, W3, Wc32);
    convert_wc<<<256, 256, 0, stream>>>(Wc32, wtc);
    matvec256<<<1, 256, 0, stream>>>(b1, W2, u);
    matvec256<<<1, 256, 0, stream>>>(u, W3, v1);
    matvec256<<<1, 256, 0, stream>>>(b2, W3, v2);

    for (int t = 0; t < T_STEPS; ++t) {
        const int*   ids = node_features + (size_t)t * NN;
        const int*   row = edge_index + (size_t)t * 2 * EE;
        const int*   col = row + EE;
        const float* w   = edge_weight + (size_t)t * EE;

        // per-timestep graph preprocessing (shared by all 3 aggs)
        init_deg_cnt<<<gN, 256, 0, stream>>>(deg, cnt, NN);
        edge_deg_cnt<<<gE, 256, 0, stream>>>(col, w, deg, cnt, EE);
        dinv_bsums<<<gN, 256, 0, stream>>>(deg, dinv, s1v, cnt, bsum, NN);
        scan_bsum<<<1, 256, 0, stream>>>(bsum, boff, NB);
        scan_final<<<gN, 256, 0, stream>>>(cnt, boff, colptr, next, NN, EE);
        fill_csr<<<gE, 256, 0, stream>>>(row, col, w, dinv, next, edges, s1v, EE);

        // Z = emb[ids] @ Wc  (embedding gather fused; output slice-major)
        mfma_gemm<<<gGemm, 256, 0, stream>>>(ids, ebf, wtc, h2, NN);

        // A·Z -> xb (also s2 = A·s1), A·(A·Z) -> h2, A·(A·A·Z) + bias -> out
        agg_sliced<<<gAgg, 256, 0, stream>>>(h2, colptr, edges, dinv,
                                             s1v, s2v, nullptr, nullptr, nullptr, nullptr,
                                             nullptr, xb, NN);
        agg_sliced<<<gAgg, 256, 0, stream>>>(xb, colptr, edges, dinv,
                                             nullptr, nullptr, nullptr, nullptr, nullptr, nullptr,
                                             nullptr, h2, NN);
        agg_sliced<<<gAgg, 256, 0, stream>>>(h2, colptr, edges, dinv,
                                             s1v, nullptr, s2v, v1, v2, b3,
                                             out + (size_t)t * NN * DD, nullptr, NN);
    }
}

// Round 4
// 2108.436 us; speedup vs baseline: 1.4115x; 1.4115x over previous
//
#include <hip/hip_runtime.h>

// Problem constants (SpatialEncoding_46943992545790)
#define T_STEPS 4
#define NN 50000
#define EE 800000
#define DD 256
#define VOCAB 64000
#define NB ((NN + 255) / 256)   // 196 scan blocks
#define SLICES 8                // feature slices: 32 bf16 = 64 B each; 3.2 MB/slice table
#define CGRP ((NN + 31) / 32)   // c-groups of 32 per slice (4 waves x 8 c per block)

typedef __attribute__((ext_vector_type(8))) short short8;
typedef __attribute__((ext_vector_type(4))) float floatx4;

// ---------------------------------------------------------------- bf16 helpers
__device__ __forceinline__ unsigned short f2bf(float f) {
    unsigned u = __float_as_uint(f);
    return (unsigned short)((u + 0x7FFFu + ((u >> 16) & 1u)) >> 16);  // RNE
}
__device__ __forceinline__ float bf2f(unsigned short s) {
    return __uint_as_float(((unsigned)s) << 16);
}

__device__ __forceinline__ void async16(const unsigned short* g, unsigned short* l) {
    __builtin_amdgcn_global_load_lds(
        (const __attribute__((address_space(1))) void*)g,
        (__attribute__((address_space(3))) void*)l, 16, 0, 0);
}

// ---------------------------------------------------------------- init
__global__ __launch_bounds__(256) void init_deg_cnt(float* __restrict__ deg,
                                                    int* __restrict__ cnt, int n) {
    int i = blockIdx.x * 256 + threadIdx.x;
    if (i < n) { deg[i] = 1.0f; cnt[i] = 0; }   // self-loop weight 1
}

// ------------------------------------------------- edge pass: deg + counts
__global__ __launch_bounds__(256) void edge_deg_cnt(const int* __restrict__ col,
                                                    const float* __restrict__ w,
                                                    float* __restrict__ deg,
                                                    int* __restrict__ cnt, int e) {
    int i = blockIdx.x * 256 + threadIdx.x;
    if (i < e) {
        int c = col[i];
        atomicAdd(&deg[c], w[i]);
        atomicAdd(&cnt[c], 1);
    }
}

// ------------------------------- fused: dinv + s1 self-seed + scan pass 1
__global__ __launch_bounds__(256) void dinv_bsums(const float* __restrict__ deg,
                                                  float* __restrict__ dinv,
                                                  float* __restrict__ s1,
                                                  const int* __restrict__ cnt,
                                                  int* __restrict__ bsum, int n) {
    int i = blockIdx.x * 256 + threadIdx.x;
    if (i < n) {
        float d = deg[i];
        float r = d > 0.0f ? rsqrtf(d) : 0.0f;
        dinv[i] = r;
        s1[i] = r * r;            // self-loop contribution to s1 = A·1
    }
    __shared__ int sm[256];
    sm[threadIdx.x] = (i < n) ? cnt[i] : 0;
    __syncthreads();
    for (int s = 128; s > 0; s >>= 1) {
        if ((int)threadIdx.x < s) sm[threadIdx.x] += sm[threadIdx.x + s];
        __syncthreads();
    }
    if (threadIdx.x == 0) bsum[blockIdx.x] = sm[0];
}

// --------------------------------------------------- parallel scan, pass 2
__global__ __launch_bounds__(256) void scan_bsum(const int* __restrict__ bsum,
                                                 int* __restrict__ boff, int nb) {
    __shared__ int sm[256];
    int v = ((int)threadIdx.x < nb) ? bsum[threadIdx.x] : 0;
    sm[threadIdx.x] = v;
    __syncthreads();
    for (int o = 1; o < 256; o <<= 1) {
        int t = (threadIdx.x >= (unsigned)o) ? sm[threadIdx.x - o] : 0;
        __syncthreads();
        sm[threadIdx.x] += t;
        __syncthreads();
    }
    if ((int)threadIdx.x < nb) boff[threadIdx.x] = sm[threadIdx.x] - v;
}

// --------------------------------------------------- parallel scan, pass 3
__global__ __launch_bounds__(256) void scan_final(const int* __restrict__ cnt,
                                                  const int* __restrict__ boff,
                                                  int* __restrict__ colptr,
                                                  int* __restrict__ next, int n, int e) {
    __shared__ int sm[256];
    int i = blockIdx.x * 256 + threadIdx.x;
    int v = (i < n) ? cnt[i] : 0;
    sm[threadIdx.x] = v;
    __syncthreads();
    for (int o = 1; o < 256; o <<= 1) {
        int t = (threadIdx.x >= (unsigned)o) ? sm[threadIdx.x - o] : 0;
        __syncthreads();
        sm[threadIdx.x] += t;
        __syncthreads();
    }
    int excl = sm[threadIdx.x] - v + boff[blockIdx.x];
    if (i < n) { colptr[i] = excl; next[i] = excl; }
    if (i == 0) colptr[n] = e;   // every edge's col is in [0,n)
}

// --------------------------------------- fill CSR (packed edges) + s1 atomics
__global__ __launch_bounds__(256) void fill_csr(const int* __restrict__ row,
                                                const int* __restrict__ col,
                                                const float* __restrict__ w,
                                                const float* __restrict__ dinv,
                                                int* __restrict__ next,
                                                int2* __restrict__ edges,
                                                float* __restrict__ s1, int e) {
    int i = blockIdx.x * 256 + threadIdx.x;
    if (i < e) {
        int r = row[i], c = col[i];
        float nm = dinv[r] * w[i] * dinv[c];
        int p = atomicAdd(&next[c], 1);
        edges[p] = make_int2(r, __float_as_int(nm));
        atomicAdd(&s1[c], nm);     // completes s1 = A·1 (self seeded in dinv_bsums)
    }
}

// --------------------------------- fp32 256x256 matmul: C = A @ B (once/launch)
__global__ __launch_bounds__(256) void matmul256(const float* __restrict__ A,
                                                 const float* __restrict__ B,
                                                 float* __restrict__ C) {
    __shared__ float arow[256];
    int i = blockIdx.x, j = threadIdx.x;
    arow[j] = A[i * 256 + j];
    __syncthreads();
    float acc = 0.f;
#pragma unroll 8
    for (int k = 0; k < 256; ++k) acc += arow[k] * B[k * 256 + j];
    C[i * 256 + j] = acc;
}

// --------------------------------- fp32 matvec: y = x @ W  (1 block, once/launch)
__global__ __launch_bounds__(256) void matvec256(const float* __restrict__ x,
                                                 const float* __restrict__ W,
                                                 float* __restrict__ y) {
    __shared__ float xs[256];
    int j = threadIdx.x;
    xs[j] = x[j];
    __syncthreads();
    float acc = 0.f;
#pragma unroll 8
    for (int k = 0; k < 256; ++k) acc += xs[k] * W[k * 256 + j];
    y[j] = acc;
}

// --------------------------------- Wc[k][n] fp32 -> wt[n][k] bf16 (transposed)
__global__ __launch_bounds__(256) void convert_wc(const float* __restrict__ Wc,
                                                  unsigned short* __restrict__ wt) {
    int n = blockIdx.x;          // 0..255
    int k = threadIdx.x;         // 0..255
    wt[n * 256 + k] = f2bf(Wc[k * 256 + n]);
}

// --------------------------------- emb fp32 -> bf16 (once per launch)
__global__ __launch_bounds__(256) void convert_emb(const float* __restrict__ emb,
                                                   unsigned short* __restrict__ ebf,
                                                   int total4) {
    int t = blockIdx.x * 256 + threadIdx.x;
    if (t < total4) {
        float4 v = ((const float4*)emb)[t];
        ushort4 o;
        o.x = f2bf(v.x); o.y = f2bf(v.y); o.z = f2bf(v.z); o.w = f2bf(v.w);
        ((ushort4*)ebf)[t] = o;
    }
}

// ------------------------------------------------------- bf16 MFMA GEMM + gather
// Z = ebf[ids[M],256] @ Wc, written SLICE-MAJOR: h2[slice][node][32] bf16
// (slice = col>>5) so aggregation slices are contiguous 3.2 MB L2-resident blocks.
// BM=128, BN=256, BK=32, 4 waves; wave = 64x128 via 4x8 grid of 16x16x32 MFMA.
__global__ __launch_bounds__(256) void mfma_gemm(const int* __restrict__ ids,
                                                 const unsigned short* __restrict__ ebf,
                                                 const unsigned short* __restrict__ wt,
                                                 unsigned short* __restrict__ h2,
                                                 int M) {
    __shared__ __align__(16) unsigned short As[128 * 32];   // 8 KB
    __shared__ __align__(16) unsigned short Bs[256 * 32];   // 16 KB

    int tid = threadIdx.x;
    int lane = tid & 63;
    int wave = tid >> 6;
    int row0 = blockIdx.x * 128;
    int wm = (wave & 1) * 64;
    int wn = (wave >> 1) * 128;
    int quad = lane >> 4;
    int cl = lane & 15;

    // A staging: 2 units/thread, u = s*256+tid; c = u>>7 (k-chunk), m = u&127
    int uA0 = tid, uA1 = 256 + tid;
    int cA0 = uA0 >> 7, mA0 = uA0 & 127;
    int cA1 = uA1 >> 7;                       // same row (uA1&127 == mA0)
    int gr = row0 + mA0; if (gr >= M) gr = M - 1;
    int id0 = ids[gr];                        // embedding gather index
    const unsigned short* srcA0 = ebf + (size_t)id0 * 256 + cA0 * 8;
    const unsigned short* srcA1 = ebf + (size_t)id0 * 256 + cA1 * 8;
    unsigned short* dstA0 = As + uA0 * 8;
    unsigned short* dstA1 = As + uA1 * 8;

    // B staging: 4 units/thread, unit s: chunk=s, n=tid
    const unsigned short* srcB = wt + (size_t)tid * 256;
    unsigned short* dstBbase = Bs + tid * 8;

    floatx4 acc[4][8] = {};

    for (int k0 = 0; k0 < 256; k0 += 32) {
        if (k0) __syncthreads();          // protect LDS from prior reads
        async16(srcA0 + k0, dstA0);
        async16(srcA1 + k0, dstA1);
#pragma unroll
        for (int s5 = 0; s5 < 4; ++s5)
            async16(srcB + s5 * 8 + k0, dstBbase + s5 * 2048);
        __syncthreads();                  // drains vmcnt before barrier

        short8 af[4], bfr[8];
#pragma unroll
        for (int i = 0; i < 4; ++i)
            af[i] = *(const short8*)&As[(quad * 128 + wm + i * 16 + cl) * 8];
#pragma unroll
        for (int j = 0; j < 8; ++j)
            bfr[j] = *(const short8*)&Bs[(quad * 256 + wn + j * 16 + cl) * 8];
#pragma unroll
        for (int i = 0; i < 4; ++i)
#pragma unroll
            for (int j = 0; j < 8; ++j)
                acc[i][j] = __builtin_amdgcn_mfma_f32_16x16x32_bf16(
                    af[i], bfr[j], acc[i][j], 0, 0, 0);
    }

    // epilogue -> slice-major: D[row=quad*4+reg][col=lane&15] per 16x16 tile
#pragma unroll
    for (int i = 0; i < 4; ++i) {
#pragma unroll
        for (int r = 0; r < 4; ++r) {
            int gr2 = row0 + wm + i * 16 + quad * 4 + r;
            if (gr2 < M) {
#pragma unroll
                for (int j = 0; j < 8; ++j) {
                    int colf = wn + j * 16 + cl;            // 0..255
                    int slice = colf >> 5, off = colf & 31;
                    h2[((size_t)slice * M + gr2) * 32 + off] = f2bf(acc[i][j][r]);
                }
            }
        }
    }
}

// ---------------------------------------- XCD-pinned sliced aggregate (bf16)
// slice = blockIdx.x % 8: round-robin workgroup->XCD dispatch pins each 3.2 MB
// feature slice to one XCD's 4 MB L2 -> all gathers L2-hit after warmup.
// Wave handles 8 dests: 8 groups x 8 lanes; lane owns 8 B of the 64 B slice row.
// Edges accumulate serially per group in registers (no cross-lane reduction),
// unrolled x2 for two independent gather chains.
// agg1 (slice 0 blocks): s2[c] = self*s1[c] + sum(norm * s1[src]).
// final: adds s2[c]*v1 + s1[c]*v2 + b3, writes fp32 row-major out.
__global__ __launch_bounds__(256) void agg_xcd(const unsigned short* __restrict__ tbl,
                                               const int* __restrict__ colptr,
                                               const int2* __restrict__ edges,
                                               const float* __restrict__ dinv,
                                               const float* __restrict__ s1,
                                               float* __restrict__ s2_out,
                                               const float* __restrict__ s2,
                                               const float* __restrict__ v1,
                                               const float* __restrict__ v2,
                                               const float* __restrict__ b3,
                                               float* __restrict__ dstf,
                                               unsigned short* __restrict__ dstb,
                                               int n) {
    int slice = blockIdx.x & 7;          // XCD-pinned slice
    int idx   = blockIdx.x >> 3;         // c-group index within slice
    int wave = threadIdx.x >> 6;
    int lane = threadIdx.x & 63;
    int g  = lane >> 3;                  // dest group 0..7
    int il = lane & 7;                   // 8 B sub-row: features il*4 .. il*4+3
    int c = idx * 32 + wave * 8 + g;
    bool act = c < n;
    int cc = act ? c : n - 1;
    int p0 = colptr[cc];
    int p1 = act ? colptr[cc + 1] : p0;
    float di = dinv[cc];
    float self = di * di;
    bool do_s2 = (s2_out != nullptr) && (slice == 0);

    const unsigned short* tb = tbl + (size_t)slice * n * 32;

    // self-loop seed
    ushort4 sv = *(const ushort4*)(tb + (size_t)cc * 32 + il * 4);
    float a0 = self * bf2f(sv.x), a1 = self * bf2f(sv.y);
    float a2 = self * bf2f(sv.z), a3 = self * bf2f(sv.w);
    float ss = 0.f;

    int j = p0;
    for (; j + 1 < p1; j += 2) {
        int2 e0 = edges[j];
        int2 e1 = edges[j + 1];
        float w0 = __int_as_float(e0.y);
        float w1 = __int_as_float(e1.y);
        ushort4 va = *(const ushort4*)(tb + (size_t)e0.x * 32 + il * 4);
        ushort4 vb = *(const ushort4*)(tb + (size_t)e1.x * 32 + il * 4);
        if (do_s2) ss += w0 * s1[e0.x] + w1 * s1[e1.x];
        a0 += w0 * bf2f(va.x) + w1 * bf2f(vb.x);
        a1 += w0 * bf2f(va.y) + w1 * bf2f(vb.y);
        a2 += w0 * bf2f(va.z) + w1 * bf2f(vb.z);
        a3 += w0 * bf2f(va.w) + w1 * bf2f(vb.w);
    }
    if (j < p1) {
        int2 e0 = edges[j];
        float w0 = __int_as_float(e0.y);
        ushort4 va = *(const ushort4*)(tb + (size_t)e0.x * 32 + il * 4);
        if (do_s2) ss += w0 * s1[e0.x];
        a0 += w0 * bf2f(va.x);
        a1 += w0 * bf2f(va.y);
        a2 += w0 * bf2f(va.z);
        a3 += w0 * bf2f(va.w);
    }

    if (do_s2 && act && il == 0) s2_out[c] = self * s1[c] + ss;

    if (act) {
        if (dstb) {
            ushort4 o;
            o.x = f2bf(a0); o.y = f2bf(a1); o.z = f2bf(a2); o.w = f2bf(a3);
            *(ushort4*)(dstb + ((size_t)slice * n + c) * 32 + il * 4) = o;
        } else {
            int f0 = slice * 32 + il * 4;
            float s1c = s1[c], s2c = s2[c];
            float4 q1 = *(const float4*)(v1 + f0);
            float4 q2 = *(const float4*)(v2 + f0);
            float4 q3 = *(const float4*)(b3 + f0);
            float4 o;
            o.x = a0 + s2c * q1.x + s1c * q2.x + q3.x;
            o.y = a1 + s2c * q1.y + s1c * q2.y + q3.y;
            o.z = a2 + s2c * q1.z + s1c * q2.z + q3.z;
            o.w = a3 + s2c * q1.w + s1c * q2.w + q3.w;
            *(float4*)(dstf + (size_t)c * 256 + f0) = o;
        }
    }
}

// ----------------------------------------------------------------------
// Linearity collapse: no nonlinearity between GCN layers, so
//   out_t = A^3 · emb[ids] · (W1 W2 W3) + (A^2 1)⊗(b1 W2 W3) + (A 1)⊗(b2 W3) + 1⊗b3
// One GEMM (embedding gather fused into A-staging) + 3 XCD-sliced aggs per t.
extern "C" void kernel_launch(void* const* d_in, const int* in_sizes, int n_in,
                              void* d_out, int out_size, void* d_ws, size_t ws_size,
                              hipStream_t stream) {
    const int*   node_features = (const int*)d_in[0];   // [T, N]
    const int*   edge_index    = (const int*)d_in[1];   // [T, 2, E]
    const float* edge_weight   = (const float*)d_in[2]; // [T, E]
    const float* emb           = (const float*)d_in[3]; // [VOCAB, D]
    const float* W1 = (const float*)d_in[4];
    const float* b1 = (const float*)d_in[5];
    const float* W2 = (const float*)d_in[6];
    const float* b2 = (const float*)d_in[7];
    const float* W3 = (const float*)d_in[8];
    const float* b3 = (const float*)d_in[9];
    float* out = (float*)d_out;

    // workspace layout
    char* ws = (char*)d_ws;
    size_t off = 0;
    auto alloc = [&](size_t bytes) -> void* {
        void* p = ws + off;
        off = (off + bytes + 255) & ~(size_t)255;
        return p;
    };
    unsigned short* ebf    = (unsigned short*)alloc((size_t)VOCAB * DD * 2); // bf16 emb
    unsigned short* xb     = (unsigned short*)alloc((size_t)NN * DD * 2);    // bf16 sliced
    unsigned short* h2     = (unsigned short*)alloc((size_t)NN * DD * 2);    // bf16 sliced
    unsigned short* wtc    = (unsigned short*)alloc((size_t)DD * DD * 2);    // Wc^T bf16
    float* Wtmp   = (float*)alloc((size_t)DD * DD * 4);   // W1@W2
    float* Wc32   = (float*)alloc((size_t)DD * DD * 4);   // W1@W2@W3
    float* u      = (float*)alloc((size_t)DD * 4);        // b1@W2
    float* v1     = (float*)alloc((size_t)DD * 4);        // b1@W2@W3
    float* v2     = (float*)alloc((size_t)DD * 4);        // b2@W3
    float* deg    = (float*)alloc((size_t)NN * 4);
    float* dinv   = (float*)alloc((size_t)NN * 4);
    float* s1v    = (float*)alloc((size_t)NN * 4);
    float* s2v    = (float*)alloc((size_t)NN * 4);
    int*   cnt    = (int*)alloc((size_t)NN * 4);
    int*   colptr = (int*)alloc((size_t)(NN + 1) * 4);
    int*   next   = (int*)alloc((size_t)NN * 4);
    int2*  edges  = (int2*)alloc((size_t)EE * 8);
    int*   bsum   = (int*)alloc((size_t)NB * 4);
    int*   boff   = (int*)alloc((size_t)NB * 4);
    (void)ws_size; (void)n_in; (void)in_sizes; (void)out_size;

    const int gN    = (NN + 255) / 256;   // == NB
    const int gE    = (EE + 255) / 256;
    const int gAgg  = SLICES * CGRP;      // 8 x 1563 = 12504 blocks
    const int gEmb  = (VOCAB * 64 + 255) / 256;
    const int gGemm = (NN + 127) / 128;

    // ---- once per launch: collapsed weights, bias vectors, bf16 emb table
    convert_emb<<<gEmb, 256, 0, stream>>>(emb, ebf, VOCAB * 64);
    matmul256<<<256, 256, 0, stream>>>(W1, W2, Wtmp);
    matmul256<<<256, 256, 0, stream>>>(Wtmp, W3, Wc32);
    convert_wc<<<256, 256, 0, stream>>>(Wc32, wtc);
    matvec256<<<1, 256, 0, stream>>>(b1, W2, u);
    matvec256<<<1, 256, 0, stream>>>(u, W3, v1);
    matvec256<<<1, 256, 0, stream>>>(b2, W3, v2);

    for (int t = 0; t < T_STEPS; ++t) {
        const int*   ids = node_features + (size_t)t * NN;
        const int*   row = edge_index + (size_t)t * 2 * EE;
        const int*   col = row + EE;
        const float* w   = edge_weight + (size_t)t * EE;

        // per-timestep graph preprocessing (shared by all 3 aggs)
        init_deg_cnt<<<gN, 256, 0, stream>>>(deg, cnt, NN);
        edge_deg_cnt<<<gE, 256, 0, stream>>>(col, w, deg, cnt, EE);
        dinv_bsums<<<gN, 256, 0, stream>>>(deg, dinv, s1v, cnt, bsum, NN);
        scan_bsum<<<1, 256, 0, stream>>>(bsum, boff, NB);
        scan_final<<<gN, 256, 0, stream>>>(cnt, boff, colptr, next, NN, EE);
        fill_csr<<<gE, 256, 0, stream>>>(row, col, w, dinv, next, edges, s1v, EE);

        // Z = emb[ids] @ Wc  (embedding gather fused; output slice-major)
        mfma_gemm<<<gGemm, 256, 0, stream>>>(ids, ebf, wtc, h2, NN);

        // A·Z -> xb (also s2 = A·s1), A·(A·Z) -> h2, A·(A·A·Z) + bias -> out
        agg_xcd<<<gAgg, 256, 0, stream>>>(h2, colptr, edges, dinv,
                                          s1v, s2v, nullptr, nullptr, nullptr, nullptr,
                                          nullptr, xb, NN);
        agg_xcd<<<gAgg, 256, 0, stream>>>(xb, colptr, edges, dinv,
                                          nullptr, nullptr, nullptr, nullptr, nullptr, nullptr,
                                          nullptr, h2, NN);
        agg_xcd<<<gAgg, 256, 0, stream>>>(h2, colptr, edges, dinv,
                                          s1v, nullptr, s2v, v1, v2, b3,
                                          out + (size_t)t * NN * DD, nullptr, NN);
    }
}